// Round 1
// baseline (30544.867 us; speedup 1.0000x reference)
//
#include <hip/hip_runtime.h>

typedef unsigned short u16;
typedef unsigned int u32;
typedef __attribute__((ext_vector_type(8))) short s8v;
typedef __attribute__((ext_vector_type(4))) float f4v;

#define NBLK 64
#define T_STEPS 512

__device__ __forceinline__ u16 f2bf(float f) {
  union { float f; u32 u; } a; a.f = f;
  u32 r = a.u + 0x7fffu + ((a.u >> 16) & 1u);
  return (u16)(r >> 16);
}

// value [B=128][D=256][T=512] f32  ->  xall [T][B][D] bf16
__global__ void xpose_kernel(const float* __restrict__ v, u16* __restrict__ xall) {
  __shared__ float tl[32][33];
  const int tx = threadIdx.x & 31;
  const int ty = threadIdx.x >> 5;
  const int t0 = blockIdx.x << 5;
  const int k0 = blockIdx.y << 5;
  const int b  = blockIdx.z;
  const float* src = v + (size_t)b * 131072 + (size_t)k0 * 512 + t0;
#pragma unroll
  for (int ii = 0; ii < 4; ++ii) {
    int i = ty + ii * 8;
    tl[i][tx] = src[(size_t)i * 512 + tx];
  }
  __syncthreads();
  u16* dst = xall + (size_t)t0 * 32768 + (size_t)b * 256 + k0;
#pragma unroll
  for (int ii = 0; ii < 4; ++ii) {
    int tt = ty + ii * 8;
    dst[(size_t)tt * 32768 + tx] = f2bf(tl[tx][tt]);
  }
}

// device-scope sense-free barrier: ctrl[0]=arrive count, ctrl[16]=generation
__device__ __forceinline__ void gridbar(u32* ctrl, u32 target) {
  __syncthreads();
  if (threadIdx.x == 0) {
    __threadfence();  // release this block's global writes
    u32 old = __hip_atomic_fetch_add(&ctrl[0], 1u, __ATOMIC_ACQ_REL, __HIP_MEMORY_SCOPE_AGENT);
    if (old == (u32)(NBLK - 1)) {
      __hip_atomic_store(&ctrl[0], 0u, __ATOMIC_RELAXED, __HIP_MEMORY_SCOPE_AGENT);
      __hip_atomic_store(&ctrl[16], target, __ATOMIC_RELEASE, __HIP_MEMORY_SCOPE_AGENT);
    } else {
      while (__hip_atomic_load(&ctrl[16], __ATOMIC_ACQUIRE, __HIP_MEMORY_SCOPE_AGENT) < target) {
        __builtin_amdgcn_s_sleep(2);
      }
    }
    __threadfence();  // acquire: invalidate caches before block's plain loads
  }
  __syncthreads();
}

// Persistent recurrent kernel.
// Grid: 64 blocks x 512 threads (8 waves). Block b owns gate-columns [16b,16b+16).
// Wave w: kq = w&3 (K quarter: kt in [10kq,10kq+10), K-space = 8 x-tiles + 32 h-tiles),
//          mh = w>>2 (batch half: rows [64mh, 64mh+64)).
// Weight B-fragments (z,r,htilde) held in VGPRs for the whole kernel.
__global__ __launch_bounds__(512) void grud_kernel(
    const float* __restrict__ delta,
    const float* __restrict__ w_dg, const float* __restrict__ b_dg,
    const float* __restrict__ w_xz, const float* __restrict__ w_hz,
    const float* __restrict__ w_xr, const float* __restrict__ w_hr,
    const float* __restrict__ w_xh, const float* __restrict__ w_hh,
    const float* __restrict__ b_z, const float* __restrict__ b_r,
    const float* __restrict__ b_h,
    const u16* __restrict__ xall,
    u16* __restrict__ hb, u16* __restrict__ qb,
    float* __restrict__ hd32,
    u32* __restrict__ ctrl,
    float* __restrict__ out) {
  __shared__ float P[8][64][32];  // 64 KB partial-reduction buffer

  const int tid  = threadIdx.x;
  const int lane = tid & 63;
  const int w    = tid >> 6;
  const int kq   = w & 3;
  const int mh   = w >> 2;
  const int l15  = lane & 15;
  const int lq   = lane >> 4;
  const int kof  = lq << 3;
  const int own0 = blockIdx.x << 4;
  const int ncol = own0 + l15;

  const float bz_l  = b_z[ncol];
  const float br_l  = b_r[ncol];
  const float bh_l  = b_h[ncol];
  const float wdg_l = w_dg[ncol];
  const float bdg_l = b_dg[ncol];

  // ---- preload weight fragments into registers (bf16) ----
  // B-frag for (gate, kt): lane holds W[k = kt*32 + kof + j][ncol], j=0..7
  s8v bwz[10], bwr[10], bwh[10];
#pragma unroll
  for (int u = 0; u < 10; ++u) {
    const int kt = kq * 10 + u;
    s8v vz, vr, vh;
#pragma unroll
    for (int j = 0; j < 8; ++j) {
      const int k = kt * 32 + kof + j;
      float fz, fr, fh;
      if (k < 256) {
        const int ko = k * 1024 + ncol;
        fz = w_xz[ko]; fr = w_xr[ko]; fh = w_xh[ko];
      } else {
        const int ko = (k - 256) * 1024 + ncol;
        fz = w_hz[ko]; fr = w_hr[ko]; fh = w_hh[ko];
      }
      vz[j] = (short)f2bf(fz);
      vr[j] = (short)f2bf(fr);
      vh[j] = (short)f2bf(fh);
    }
    bwz[u] = vz; bwr[u] = vr; bwh[u] = vh;
  }

  const int r0 = (mh << 6) + l15;  // A-frag row base for this wave
  u32 bt = 0;
  float zreg[4][4];

  for (int t = 0; t < T_STEPS; ++t) {
    const u16* xt = xall + (size_t)t * 32768;
    const float dnext = delta[(t < T_STEPS - 1) ? (t + 1) : (T_STEPS - 1)];

    // ================= stage A: z, r =================
    f4v az[4], ar[4];
#pragma unroll
    for (int mt = 0; mt < 4; ++mt) {
      az[mt] = (f4v){0.f, 0.f, 0.f, 0.f};
      ar[mt] = (f4v){0.f, 0.f, 0.f, 0.f};
    }
#pragma unroll
    for (int u = 0; u < 10; ++u) {
      const int kt = kq * 10 + u;
      const u16* ab;
      int stride;
      if (kt < 8) { ab = xt + kt * 32 + kof; stride = 256; }
      else        { ab = hb + (kt - 8) * 32 + kof; stride = 1024; }
#pragma unroll
      for (int mt = 0; mt < 4; ++mt) {
        s8v a = *(const s8v*)(ab + (size_t)(r0 + (mt << 4)) * stride);
        az[mt] = __builtin_amdgcn_mfma_f32_16x16x32_bf16(a, bwz[u], az[mt], 0, 0, 0);
        ar[mt] = __builtin_amdgcn_mfma_f32_16x16x32_bf16(a, bwr[u], ar[mt], 0, 0, 0);
      }
    }
    // K-partials -> LDS
#pragma unroll
    for (int mt = 0; mt < 4; ++mt)
#pragma unroll
      for (int jj = 0; jj < 4; ++jj) {
        const int rr = (mt << 4) + (lq << 2) + jj;
        P[w][rr][l15]      = az[mt][jj];
        P[w][rr][16 + l15] = ar[mt][jj];
      }
    __syncthreads();
    if (kq <= 1) {  // waves 0,4: z-absorb; waves 1,5: r-absorb
      const bool isZ = (kq == 0);
      const float bias = isZ ? bz_l : br_l;
      const int cb = isZ ? l15 : (16 + l15);
      const int g0 = mh * 4;
#pragma unroll
      for (int mt = 0; mt < 4; ++mt)
#pragma unroll
        for (int jj = 0; jj < 4; ++jj) {
          const int rr = (mt << 4) + (lq << 2) + jj;
          float s = bias + P[g0][rr][cb] + P[g0 + 1][rr][cb] +
                    P[g0 + 2][rr][cb] + P[g0 + 3][rr][cb];
          float g = 1.f / (1.f + expf(-s));
          if (isZ) {
            zreg[mt][jj] = g;
          } else {
            const int row = (mh << 6) + rr;
            float d = hd32[row * 1024 + ncol];       // d = gamma_t * h_{t-1}
            qb[row * 1024 + ncol] = f2bf(g * d);     // q = r * d
          }
        }
    }
    ++bt;
    gridbar(ctrl, bt);

    // ================= stage B: h_tilde + update =================
    f4v ah[4];
#pragma unroll
    for (int mt = 0; mt < 4; ++mt) ah[mt] = (f4v){0.f, 0.f, 0.f, 0.f};
#pragma unroll
    for (int u = 0; u < 10; ++u) {
      const int kt = kq * 10 + u;
      const u16* ab;
      int stride;
      if (kt < 8) { ab = xt + kt * 32 + kof; stride = 256; }
      else        { ab = qb + (kt - 8) * 32 + kof; stride = 1024; }
#pragma unroll
      for (int mt = 0; mt < 4; ++mt) {
        s8v a = *(const s8v*)(ab + (size_t)(r0 + (mt << 4)) * stride);
        ah[mt] = __builtin_amdgcn_mfma_f32_16x16x32_bf16(a, bwh[u], ah[mt], 0, 0, 0);
      }
    }
    float (*Pb)[64][16] = (float (*)[64][16])(&P[0][0][0]);
#pragma unroll
    for (int mt = 0; mt < 4; ++mt)
#pragma unroll
      for (int jj = 0; jj < 4; ++jj) {
        const int rr = (mt << 4) + (lq << 2) + jj;
        Pb[w][rr][l15] = ah[mt][jj];
      }
    __syncthreads();
    if (kq == 0) {  // waves 0,4 hold zreg and finish the update
      const int g0 = mh * 4;
#pragma unroll
      for (int mt = 0; mt < 4; ++mt)
#pragma unroll
        for (int jj = 0; jj < 4; ++jj) {
          const int rr = (mt << 4) + (lq << 2) + jj;
          float s = bh_l + Pb[g0][rr][l15] + Pb[g0 + 1][rr][l15] +
                    Pb[g0 + 2][rr][l15] + Pb[g0 + 3][rr][l15];
          float ht = tanhf(s);
          float z = zreg[mt][jj];
          const int row = (mh << 6) + rr;
          float d = hd32[row * 1024 + ncol];
          float hn = (1.f - z) * d + z * ht;
          out[(size_t)row * (512 * 1024) + (size_t)t * 1024 + ncol] = hn;
          if (t == T_STEPS - 1) {
            out[(size_t)67108864 + (size_t)row * 1024 + ncol] = hn;  // h_last
          } else {
            float gam = expf(-fmaxf(0.f, wdg_l * dnext + bdg_l));
            float hd = gam * hn;  // pre-decay for step t+1
            hd32[row * 1024 + ncol] = hd;
            hb[row * 1024 + ncol] = f2bf(hd);
          }
        }
    }
    ++bt;
    gridbar(ctrl, bt);
  }
}

extern "C" void kernel_launch(void* const* d_in, const int* in_sizes, int n_in,
                              void* d_out, int out_size, void* d_ws, size_t ws_size,
                              hipStream_t stream) {
  (void)in_sizes; (void)n_in; (void)out_size; (void)ws_size;
  const float* value = (const float*)d_in[0];
  const float* delta = (const float*)d_in[1];
  const float* w_dg  = (const float*)d_in[2];
  const float* w_xz  = (const float*)d_in[3];
  const float* w_hz  = (const float*)d_in[4];
  const float* w_xr  = (const float*)d_in[5];
  const float* w_hr  = (const float*)d_in[6];
  const float* w_xh  = (const float*)d_in[7];
  const float* w_hh  = (const float*)d_in[8];
  const float* b_dg  = (const float*)d_in[9];
  const float* b_z   = (const float*)d_in[10];
  const float* b_r   = (const float*)d_in[11];
  const float* b_h   = (const float*)d_in[12];

  char* ws = (char*)d_ws;
  u16*  hb   = (u16*)(ws + 0);          // [128][1024] bf16: gamma_{t+1}*h_t
  u16*  qb   = (u16*)(ws + 262144);     // [128][1024] bf16: r*d
  float* hd32 = (float*)(ws + 524288);  // [128][1024] f32: gamma_{t+1}*h_t
  u32*  ctrl = (u32*)(ws + 1048576);    // barrier state
  u16*  xall = (u16*)(ws + 1052672);    // [512][128][256] bf16
  float* out = (float*)d_out;

  // zero state + barrier control
  hipMemsetAsync(d_ws, 0, 1048832, stream);
  // transpose/convert x
  xpose_kernel<<<dim3(16, 8, 128), 256, 0, stream>>>(value, xall);
  // persistent recurrence
  grud_kernel<<<NBLK, 512, 0, stream>>>(delta, w_dg, b_dg, w_xz, w_hz, w_xr, w_hr,
                                        w_xh, w_hh, b_z, b_r, b_h,
                                        xall, hb, qb, hd32, ctrl, out);
}